// Round 8
// baseline (985.090 us; speedup 1.0000x reference)
//
#include <hip/hip_runtime.h>
#include <math.h>

// ---- problem constants ----
#define B_     4
#define NIMG_  4
#define H_     80
#define W_     80
#define C_     256
#define NH_    8
#define HW_    6400     // H*W
#define NQ_    25600    // NIMG*H*W
#define NPIX_  102400   // B*NQ
#define L3_    200      // 2*10*10 sample points

// ---- workspace layout (float offsets), regions reused across stages ----
#define WS_QH   0u
#define WS_KH   3276800u
#define WS_V2   6553600u
#define WS_FIN2 9830400u
#define WS_OFF  3276800u
#define WS_A2   9830400u
#define WS_Q3   0u
#define WS_KF   3276800u
#define WS_VF   6553600u
#define WS_CRD  9830400u
#define WS_KS   9832800u
#define WS_VS   9858400u
#define WS_O3   3276800u

// branchless bilinear 9-ch sample from a g-slice of fin2 (48-float records)
__device__ __forceinline__ void bilin9(const float* __restrict__ finb,
        float py, float px, float* __restrict__ s) {
    float y0f = floorf(py), x0f = floorf(px);
    float wy = py - y0f, wx = px - x0f;
    float wy0 = 1.f - wy, wx0 = 1.f - wx;
    float vy0 = (y0f >= 0.f && y0f <= 79.f) ? 1.f : 0.f;
    float vy1 = (y0f >= -1.f && y0f <= 78.f) ? 1.f : 0.f;
    float vx0 = (x0f >= 0.f && x0f <= 79.f) ? 1.f : 0.f;
    float vx1 = (x0f >= -1.f && x0f <= 78.f) ? 1.f : 0.f;
    int yi0 = (int)fminf(fmaxf(y0f, 0.f), 79.f);
    int yi1 = (int)fminf(fmaxf(y0f + 1.f, 0.f), 79.f);
    int xi0 = (int)fminf(fmaxf(x0f, 0.f), 79.f);
    int xi1 = (int)fminf(fmaxf(x0f + 1.f, 0.f), 79.f);
    float w00 = wy0 * wx0 * vy0 * vx0;
    float w01 = wy0 * wx  * vy0 * vx1;
    float w10 = wy  * wx0 * vy1 * vx0;
    float w11 = wy  * wx  * vy1 * vx1;
    const float4* c00 = (const float4*)(finb + (size_t)(yi0 * W_ + xi0) * 48);
    const float4* c01 = (const float4*)(finb + (size_t)(yi0 * W_ + xi1) * 48);
    const float4* c10 = (const float4*)(finb + (size_t)(yi1 * W_ + xi0) * 48);
    const float4* c11 = (const float4*)(finb + (size_t)(yi1 * W_ + xi1) * 48);
    {
        float4 p0 = c00[0], p1 = c00[1], p2 = c00[2];
        s[0] = w00 * p0.x; s[1] = w00 * p0.y; s[2] = w00 * p0.z; s[3] = w00 * p0.w;
        s[4] = w00 * p1.x; s[5] = w00 * p1.y; s[6] = w00 * p1.z; s[7] = w00 * p1.w;
        s[8] = w00 * p2.x;
    }
    {
        float4 p0 = c01[0], p1 = c01[1], p2 = c01[2];
        s[0] += w01 * p0.x; s[1] += w01 * p0.y; s[2] += w01 * p0.z; s[3] += w01 * p0.w;
        s[4] += w01 * p1.x; s[5] += w01 * p1.y; s[6] += w01 * p1.z; s[7] += w01 * p1.w;
        s[8] += w01 * p2.x;
    }
    {
        float4 p0 = c10[0], p1 = c10[1], p2 = c10[2];
        s[0] += w10 * p0.x; s[1] += w10 * p0.y; s[2] += w10 * p0.z; s[3] += w10 * p0.w;
        s[4] += w10 * p1.x; s[5] += w10 * p1.y; s[6] += w10 * p1.z; s[7] += w10 * p1.w;
        s[8] += w10 * p2.x;
    }
    {
        float4 p0 = c11[0], p1 = c11[1], p2 = c11[2];
        s[0] += w11 * p0.x; s[1] += w11 * p0.y; s[2] += w11 * p0.z; s[3] += w11 * p0.w;
        s[4] += w11 * p1.x; s[5] += w11 * p1.y; s[6] += w11 * p1.z; s[7] += w11 * p1.w;
        s[8] += w11 * p2.x;
    }
}

// ============================================================
// K1: qh/kh = xb @ W_qkv + b_qkv, split into the two 32-ch halves
// ============================================================
__global__ __launch_bounds__(256) void k_qkv(const float* __restrict__ x,
        const float* __restrict__ Wq, const float* __restrict__ bq,
        float* __restrict__ qh, float* __restrict__ kh) {
    __shared__ __align__(16) float xs[32][256];
    int t = threadIdx.x;
    int row0 = blockIdx.x * 32;
    for (int it = 0; it < 8; ++it) {
        int idx = t + it * 256;
        int r = idx >> 6;
        int f4 = idx & 63;
        int row = row0 + r;
        int b = row / NQ_, n = row % NQ_;
        const float4* src = (const float4*)(x + ((size_t)n * B_ + b) * C_);
        ((float4*)&xs[r][0])[f4] = src[f4];
    }
    __syncthreads();
    int j = t & 63;
    int rbase = (t >> 6) * 8;
    float acc[8];
    #pragma unroll
    for (int r = 0; r < 8; ++r) acc[r] = 0.f;
    for (int c4 = 0; c4 < 64; ++c4) {
        float w0 = Wq[(c4 * 4 + 0) * 64 + j];
        float w1 = Wq[(c4 * 4 + 1) * 64 + j];
        float w2 = Wq[(c4 * 4 + 2) * 64 + j];
        float w3 = Wq[(c4 * 4 + 3) * 64 + j];
        #pragma unroll
        for (int r = 0; r < 8; ++r) {
            float4 xv = ((const float4*)&xs[rbase + r][0])[c4];
            acc[r] += xv.x * w0 + xv.y * w1 + xv.z * w2 + xv.w * w3;
        }
    }
    float bias = bq[j];
    #pragma unroll
    for (int r = 0; r < 8; ++r) {
        int row = row0 + rbase + r;
        float vres = acc[r] + bias;
        if (j < 32) qh[(size_t)row * 32 + j] = vres;
        else        kh[(size_t)row * 32 + (j - 32)] = vres;
    }
}

// ============================================================
// K2: fin2 (g-interleaved 48-float records) + v2 (32ch) per pixel.
// ============================================================
__global__ __launch_bounds__(256) void k_fin_v2(const float* __restrict__ qh,
        const float* __restrict__ kh,
        const float* __restrict__ Wfc, const float* __restrict__ bfc,
        const float* __restrict__ Wval, const float* __restrict__ bval,
        float* __restrict__ fin2, float* __restrict__ v2) {
    __shared__ float WvalL[1024], WfcL[144], bfcL[9], bvalL[32];
    int t = threadIdx.x;
    for (int d = t; d < 1024; d += 256) WvalL[d] = Wval[d];
    if (t < 144) WfcL[t] = Wfc[t];
    if (t >= 160 && t < 169) bfcL[t - 160] = bfc[t - 160];
    if (t >= 192 && t < 224) bvalL[t - 192] = bval[t - 192];
    __syncthreads();
    int P = blockIdx.x * 256 + t;
    int b = P / NQ_, nq = P % NQ_;
    int n = nq / HW_, hw = nq % HW_;
    int bn = b * NIMG_ + n;
    float q[64];
    const float4* qp = (const float4*)(qh + (size_t)P * 32);
    const float4* kp = (const float4*)(kh + (size_t)P * 32);
    #pragma unroll
    for (int i = 0; i < 8; ++i) ((float4*)q)[i] = qp[i];
    #pragma unroll
    for (int i = 0; i < 8; ++i) ((float4*)q)[8 + i] = kp[i];
    float fo[36];
    #pragma unroll
    for (int k = 0; k < 4; ++k)
        #pragma unroll
        for (int o = 0; o < 9; ++o) fo[k * 9 + o] = bfcL[o];
    for (int c = 0; c < 16; ++c) {
        #pragma unroll
        for (int o = 0; o < 9; ++o) {
            float wv = WfcL[o * 16 + c];
            #pragma unroll
            for (int k = 0; k < 4; ++k) fo[k * 9 + o] += wv * q[c * 4 + k];
        }
    }
    float* fp = fin2 + ((size_t)bn * HW_ + hw) * 48;
    #pragma unroll
    for (int g = 0; g < 4; ++g) {
        ((float4*)fp)[g * 3 + 0] = make_float4(fo[g * 9 + 0], fo[g * 9 + 1], fo[g * 9 + 2], fo[g * 9 + 3]);
        ((float4*)fp)[g * 3 + 1] = make_float4(fo[g * 9 + 4], fo[g * 9 + 5], fo[g * 9 + 6], fo[g * 9 + 7]);
        ((float4*)fp)[g * 3 + 2] = make_float4(fo[g * 9 + 8], 0.f, 0.f, 0.f);
    }
    float vo[32];
    #pragma unroll
    for (int j = 0; j < 32; ++j) vo[j] = bvalL[j];
    for (int c = 0; c < 32; ++c) {
        float qc = q[32 + c];
        #pragma unroll
        for (int j = 0; j < 32; ++j) vo[j] += qc * WvalL[c * 32 + j];
    }
    float* vp = v2 + ((size_t)bn * HW_ + hw) * 32;
    #pragma unroll
    for (int i = 0; i < 8; ++i) ((float4*)vp)[i] = ((float4*)vo)[i];
}

// ============================================================
// K3 (R8): 4 lanes per pixel, split by g. Grid 1600 (was 400 ->
// only 6.25 waves/CU, latency-starved). Quad covers the full 192B
// fin2 record (3 float4 per lane); shfl_xor(1,2) reduces acc[18];
// bias counted once via g==0 init; lane 0 writes 9 float2.
// ============================================================
__global__ __launch_bounds__(256) void k_offconv(const float* __restrict__ fin2,
        const float* __restrict__ Wdoff, const float* __restrict__ bdoff,
        float* __restrict__ off) {
    __shared__ float Wl[5832];  // [tap][c36][o18]
    int t = threadIdx.x;
    for (int d = t; d < 5832; d += 256) {
        int tap = d / 648, r = d % 648, c = r / 18, o = r % 18;
        Wl[d] = Wdoff[(o * 36 + c) * 9 + tap];
    }
    __syncthreads();
    int P = blockIdx.x * 64 + (t >> 2);
    int g = t & 3;
    int bn = P / HW_, hw = P % HW_;
    int h = hw / W_, w = hw % W_;
    float acc[18];
    #pragma unroll
    for (int o = 0; o < 18; ++o) acc[o] = (g == 0) ? bdoff[o] : 0.f;
    for (int ky = 0; ky < 3; ++ky) {
        int hh = h + ky - 1;
        if (hh < 0 || hh >= H_) continue;
        for (int kx = 0; kx < 3; ++kx) {
            int ww = w + kx - 1;
            if (ww < 0 || ww >= W_) continue;
            int sp = hh * W_ + ww;
            const float4* base = (const float4*)(fin2 + ((size_t)bn * HW_ + sp) * 48 + g * 12);
            float4 p0 = base[0], p1 = base[1], p2 = base[2];
            float vals[9] = {p0.x, p0.y, p0.z, p0.w, p1.x, p1.y, p1.z, p1.w, p2.x};
            const float* wl = Wl + (ky * 3 + kx) * 648 + g * 9 * 18;
            #pragma unroll
            for (int idx = 0; idx < 9; ++idx) {
                const float* w0 = wl + idx * 18;
                float vv = vals[idx];
                #pragma unroll
                for (int o = 0; o < 18; ++o) acc[o] += vv * w0[o];
            }
        }
    }
    #pragma unroll
    for (int o = 0; o < 18; ++o) {
        acc[o] += __shfl_xor(acc[o], 1);
        acc[o] += __shfl_xor(acc[o], 2);
    }
    if (g == 0) {
        float2* op = (float2*)(off + (size_t)P * 18);
        #pragma unroll
        for (int o2 = 0; o2 < 9; ++o2)
            op[o2] = make_float2(acc[o2 * 2], acc[o2 * 2 + 1]);
    }
}

// ============================================================
// K4 (R4 version, best measured 148us): 1 px/thread, per-g weights
// in LDS (broadcast reads), fin2 48B records, XCD chunk swizzle.
// R5/R6/R7 attempts (2px, scalar weights) all neutral-or-worse:
// kernel is latency-pinned at ~150us; leave as-is.
// ============================================================
__global__ __launch_bounds__(256, 4) void k_depst(const float* __restrict__ fin2,
        const float* __restrict__ off, const float* __restrict__ Wdep,
        const float* __restrict__ bdep, const float* __restrict__ Wst,
        const float* __restrict__ bst, const float* __restrict__ rate2p,
        float* __restrict__ out) {
    __shared__ __align__(16) float wdepL[2268];   // [k][i][o28]
    __shared__ __align__(16) float wstL[1728];    // [i][o64]
    __shared__ float bdepL[27];
    __shared__ float bstL[64];
    int t = threadIdx.x;
    int bx = blockIdx.x;
    int u = (bx & 7) * 200 + (bx >> 3);   // bijective, 1600 % 8 == 0
    int chunk = u >> 2, g = u & 3;
    for (int d = t; d < 2268; d += 256) {
        int k = d / 252, r2 = d % 252;
        int i = r2 / 28, o = r2 % 28;
        wdepL[d] = (o < 27) ? Wdep[(size_t)(g * 27 + o) * 81 + i * 9 + k] : 0.f;
    }
    for (int d = t; d < 1728; d += 256) {
        int i = d >> 6, o = d & 63;
        wstL[d] = Wst[g * 1728 + o * 27 + i];
    }
    if (t < 27) bdepL[t] = bdep[g * 27 + t];
    if (t >= 32 && t < 96) bstL[t - 32] = bst[g * 64 + (t - 32)];
    __syncthreads();
    int P = chunk * 256 + t;
    int bn = P / HW_, hw = P % HW_;
    int h = hw / W_, w = hw % W_;
    int b = bn >> 2, n = bn & 3;
    const float* finb = fin2 + (size_t)bn * (HW_ * 48) + g * 12;
    float2 offs[9];
    {
        const float2* op2 = (const float2*)(off + (size_t)P * 18);
        #pragma unroll
        for (int k = 0; k < 9; ++k) offs[k] = op2[k];
    }
    float acc[27];
    #pragma unroll
    for (int o = 0; o < 27; ++o) acc[o] = 0.f;
    float hf = (float)h, wf = (float)w;
    #pragma unroll 1
    for (int k = 0; k < 9; ++k) {
        float py = hf + (float)(k / 3 - 1) + offs[k].x;
        float px = wf + (float)(k % 3 - 1) + offs[k].y;
        float s[9];
        bilin9(finb, py, px, s);
        const float* wk = wdepL + k * 252;
        #pragma unroll
        for (int i = 0; i < 9; ++i) {
            float si = s[i];
            const float4* rw = (const float4*)(wk + i * 28);
            float4 q0 = rw[0], q1 = rw[1], q2 = rw[2], q3v = rw[3];
            float4 q4 = rw[4], q5 = rw[5], q6 = rw[6];
            acc[0]  += si * q0.x;  acc[1]  += si * q0.y;  acc[2]  += si * q0.z;  acc[3]  += si * q0.w;
            acc[4]  += si * q1.x;  acc[5]  += si * q1.y;  acc[6]  += si * q1.z;  acc[7]  += si * q1.w;
            acc[8]  += si * q2.x;  acc[9]  += si * q2.y;  acc[10] += si * q2.z;  acc[11] += si * q2.w;
            acc[12] += si * q3v.x; acc[13] += si * q3v.y; acc[14] += si * q3v.z; acc[15] += si * q3v.w;
            acc[16] += si * q4.x;  acc[17] += si * q4.y;  acc[18] += si * q4.z;  acc[19] += si * q4.w;
            acc[20] += si * q5.x;  acc[21] += si * q5.y;  acc[22] += si * q5.z;  acc[23] += si * q5.w;
            acc[24] += si * q6.x;  acc[25] += si * q6.y;  acc[26] += si * q6.z;
        }
    }
    #pragma unroll
    for (int i = 0; i < 27; ++i) acc[i] += bdepL[i];
    float r2v = rate2p[0];
    float* ob = out + ((size_t)(n * HW_ + hw) * B_ + b) * C_ + g * 64;
    #pragma unroll 1
    for (int half = 0; half < 2; ++half) {
        float ro[32];
        #pragma unroll
        for (int o = 0; o < 32; ++o) ro[o] = bstL[half * 32 + o];
        #pragma unroll
        for (int i = 0; i < 27; ++i) {
            float ai = acc[i];
            const float4* rw = (const float4*)(wstL + i * 64 + half * 32);
            #pragma unroll
            for (int j = 0; j < 8; ++j) {
                float4 wv = rw[j];
                ro[j * 4 + 0] += ai * wv.x;
                ro[j * 4 + 1] += ai * wv.y;
                ro[j * 4 + 2] += ai * wv.z;
                ro[j * 4 + 3] += ai * wv.w;
            }
        }
        float4* obv = (float4*)(ob + half * 32);
        #pragma unroll
        for (int o4 = 0; o4 < 8; ++o4)
            obv[o4] = make_float4(r2v * ro[o4 * 4 + 0], r2v * ro[o4 * 4 + 1],
                                  r2v * ro[o4 * 4 + 2], r2v * ro[o4 * 4 + 3]);
    }
}

// ============================================================
// K5 (R8): 2D deformable attention, 4 lanes per pixel by head-pair.
// Grid 1600 (was 400 -> 1.56 waves/SIMD, fully latency-exposed).
// Lane hp handles heads {2hp,2hp+1}: 1/4 the GEMV+gather chain,
// 4x the waves. Out-projection: per-lane partial over its 8 a2v
// dims, shfl_xor(1,2) reduce, each lane stores its 8-float slice.
// ============================================================
__global__ __launch_bounds__(256) void k_attn2d(const float* __restrict__ qh,
        const float* __restrict__ v2,
        const float* __restrict__ Woff, const float* __restrict__ boff,
        const float* __restrict__ Watt, const float* __restrict__ batt,
        const float* __restrict__ Wout, const float* __restrict__ bout,
        float* __restrict__ a2) {
    __shared__ __align__(16) float WoffL[2048], WattL[1024], WoutL[1024];
    __shared__ __align__(16) float boffL[64], battL[32], boutL[32];
    int t = threadIdx.x;
    for (int d = t; d < 2048; d += 256) WoffL[d] = Woff[d];
    for (int d = t; d < 1024; d += 256) { WattL[d] = Watt[d]; WoutL[d] = Wout[d]; }
    if (t < 64) boffL[t] = boff[t];
    else if (t < 96) battL[t - 64] = batt[t - 64];
    else if (t < 128) boutL[t - 96] = bout[t - 96];
    __syncthreads();
    int P = blockIdx.x * 64 + (t >> 2);
    int hp = t & 3;
    int b = P / NQ_, nq = P % NQ_;
    int n = nq / HW_, hw = nq % HW_;
    int h = hw / W_, w = hw % W_;
    int bn = b * NIMG_ + n;
    float q[32];
    const float4* qp = (const float4*)(qh + (size_t)P * 32);
    #pragma unroll
    for (int i = 0; i < 8; ++i) ((float4*)q)[i] = qp[i];
    const float* vbase = v2 + (size_t)bn * HW_ * 32;
    float av8[8];
    #pragma unroll
    for (int i = 0; i < 8; ++i) av8[i] = 0.f;
    #pragma unroll
    for (int u2 = 0; u2 < 2; ++u2) {
        int nh = hp * 2 + u2;
        float t0 = battL[nh * 4 + 0], t1 = battL[nh * 4 + 1];
        float t2 = battL[nh * 4 + 2], t3 = battL[nh * 4 + 3];
        for (int c = 0; c < 32; ++c) {
            float qc = q[c];
            float4 wr = *(const float4*)(WattL + c * 32 + nh * 4);
            t0 += qc * wr.x; t1 += qc * wr.y; t2 += qc * wr.z; t3 += qc * wr.w;
        }
        float m = fmaxf(fmaxf(t0, t1), fmaxf(t2, t3));
        float e0 = expf(t0 - m), e1 = expf(t1 - m), e2 = expf(t2 - m), e3 = expf(t3 - m);
        float inv = 1.f / (e0 + e1 + e2 + e3);
        float pk[4] = {e0 * inv, e1 * inv, e2 * inv, e3 * inv};
        #pragma unroll
        for (int kk = 0; kk < 4; ++kk) {
            int j0 = nh * 8 + kk * 2;
            float ox = boffL[j0], oy = boffL[j0 + 1];
            for (int c = 0; c < 32; ++c) {
                float qc = q[c];
                float2 wv2 = *(const float2*)(WoffL + c * 64 + j0);
                ox += qc * wv2.x;
                oy += qc * wv2.y;
            }
            float ppx = (float)w + ox * (79.f / 80.f);
            float ppy = (float)h + oy * (79.f / 80.f);
            float x0 = floorf(ppx), y0 = floorf(ppy);
            float wx = ppx - x0, wy = ppy - y0;
            float s0 = 0.f, s1 = 0.f, s2 = 0.f, s3 = 0.f;
            #pragma unroll
            for (int cy = 0; cy < 2; ++cy) {
                float yf = y0 + (float)cy;
                if (yf < 0.f || yf > 79.f) continue;
                float wyf = cy ? wy : 1.f - wy;
                int yi = (int)yf;
                #pragma unroll
                for (int cx = 0; cx < 2; ++cx) {
                    float xf = x0 + (float)cx;
                    if (xf < 0.f || xf > 79.f) continue;
                    float wgt = wyf * (cx ? wx : 1.f - wx);
                    int xi = (int)xf;
                    float4 vv = *(const float4*)(vbase + ((size_t)yi * W_ + xi) * 32 + nh * 4);
                    s0 += wgt * vv.x; s1 += wgt * vv.y; s2 += wgt * vv.z; s3 += wgt * vv.w;
                }
            }
            float p = pk[kk];
            av8[u2 * 4 + 0] += p * s0; av8[u2 * 4 + 1] += p * s1;
            av8[u2 * 4 + 2] += p * s2; av8[u2 * 4 + 3] += p * s3;
        }
    }
    // out-projection: partial over this lane's 8 a2v dims (c = hp*8+j)
    float ro[32];
    #pragma unroll
    for (int o = 0; o < 32; ++o) ro[o] = 0.f;
    #pragma unroll
    for (int j = 0; j < 8; ++j) {
        float ac = av8[j];
        const float* wr = WoutL + (hp * 8 + j) * 32;
        #pragma unroll
        for (int o = 0; o < 32; ++o) ro[o] += ac * wr[o];
    }
    #pragma unroll
    for (int o = 0; o < 32; ++o) {
        ro[o] += __shfl_xor(ro[o], 1);
        ro[o] += __shfl_xor(ro[o], 2);
    }
    float* op = a2 + ((size_t)bn * HW_ + hw) * 32 + hp * 8;
    float outv[8];
    #pragma unroll
    for (int j = 0; j < 8; ++j) outv[j] = ro[hp * 8 + j] + boutL[hp * 8 + j];
    ((float4*)op)[0] = ((float4*)outv)[0];
    ((float4*)op)[1] = ((float4*)outv)[1];
}

// ============================================================
// K6 (R8): q3/kf/vf projections, 4 lanes per pixel. Grid 1600.
// Lane qq computes outputs [qq*8, qq*8+8) of all three projections;
// quad stores are contiguous 128B per pixel per tensor.
// ============================================================
__global__ __launch_bounds__(256) void k_qkv3(const float* __restrict__ a2,
        const float* __restrict__ Wq3, const float* __restrict__ bq3,
        const float* __restrict__ Wk3, const float* __restrict__ bk3,
        const float* __restrict__ Wv3, const float* __restrict__ bv3,
        float* __restrict__ q3, float* __restrict__ kf, float* __restrict__ vf) {
    __shared__ __align__(16) float Wq3L[1024], Wk3L[1024], Wv3L[1024];
    __shared__ float bq3L[32], bk3L[32], bv3L[32];
    int t = threadIdx.x;
    for (int d = t; d < 1024; d += 256) {
        Wq3L[d] = Wq3[d]; Wk3L[d] = Wk3[d]; Wv3L[d] = Wv3[d];
    }
    if (t < 32) { bq3L[t] = bq3[t]; bk3L[t] = bk3[t]; bv3L[t] = bv3[t]; }
    __syncthreads();
    int idx = blockIdx.x * 64 + (t >> 2);
    int qq = t & 3;
    int bn = idx / HW_, hw = idx % HW_;
    int b = bn >> 2, n = bn & 3;
    int ns = (n == 0) ? 0 : n - 1;
    const float* src = a2 + ((size_t)(b * 4 + ns) * HW_ + hw) * 32;
    float v[32];
    #pragma unroll
    for (int i = 0; i < 8; ++i) ((float4*)v)[i] = ((const float4*)src)[i];
    float oq[8], ok[8], ov[8];
    #pragma unroll
    for (int oo = 0; oo < 8; ++oo) {
        int o = qq * 8 + oo;
        float aq = bq3L[o], ak = bk3L[o], av = bv3L[o];
        #pragma unroll
        for (int c = 0; c < 32; ++c) {
            aq += Wq3L[o * 32 + c] * v[c];
            ak += Wk3L[o * 32 + c] * v[c];
            av += Wv3L[o * 32 + c] * v[c];
        }
        oq[oo] = aq; ok[oo] = ak; ov[oo] = av;
    }
    float* qo = q3 + (size_t)idx * 32 + qq * 8;
    float* ko = kf + (size_t)idx * 32 + qq * 8;
    float* vo = vf + (size_t)idx * 32 + qq * 8;
    #pragma unroll
    for (int i = 0; i < 2; ++i) {
        ((float4*)qo)[i] = ((float4*)oq)[i];
        ((float4*)ko)[i] = ((float4*)ok)[i];
        ((float4*)vo)[i] = ((float4*)ov)[i];
    }
}

// ============================================================
// K7: strided conv3d (W_offA) + gelu + W_offB + tanh*OSC -> sample coords
// ============================================================
__global__ __launch_bounds__(256) void k_offs3d(const float* __restrict__ q3,
        const float* __restrict__ WoffA, const float* __restrict__ boffA,
        const float* __restrict__ WoffB, const float* __restrict__ boffB,
        float* __restrict__ coords) {
    __shared__ float red[4][128];
    __shared__ float hidl[128];
    int t = threadIdx.x;
    int blk = blockIdx.x;
    int zo = blk / 100, r = blk % 100, ho = r / 10, wo = r % 10;
    float acc[4][32];
    #pragma unroll
    for (int b = 0; b < 4; ++b)
        #pragma unroll
        for (int o = 0; o < 32; ++o) acc[b][o] = 0.f;
    for (int tap = t; tap < 400; tap += 256) {
        int kz = tap / 100, r2 = tap % 100, ky = r2 / 10, kx = r2 % 10;
        int zi = zo * 2 + kz - 1, hi = ho * 8 + ky - 1, wi = wo * 8 + kx - 1;
        if (zi < 0 || zi >= NIMG_ || hi < 0 || hi >= H_ || wi < 0 || wi >= W_) continue;
        const float* wb = WoffA + tap;
        int sp = hi * W_ + wi;
        for (int c = 0; c < 32; ++c) {
            float vb[4];
            #pragma unroll
            for (int b = 0; b < 4; ++b)
                vb[b] = q3[((size_t)(b * 4 + zi) * HW_ + sp) * 32 + c];
            #pragma unroll
            for (int o = 0; o < 32; ++o) {
                float wv = wb[(o * 32 + c) * 400];
                #pragma unroll
                for (int b = 0; b < 4; ++b) acc[b][o] += vb[b] * wv;
            }
        }
    }
    #pragma unroll
    for (int b = 0; b < 4; ++b)
        #pragma unroll
        for (int o = 0; o < 32; ++o)
            for (int sh = 32; sh >= 1; sh >>= 1)
                acc[b][o] += __shfl_xor(acc[b][o], sh);
    int lane = t & 63, wv = t >> 6;
    if (lane == 0)
        for (int b = 0; b < 4; ++b)
            for (int o = 0; o < 32; ++o) red[wv][b * 32 + o] = acc[b][o];
    __syncthreads();
    if (t < 128) {
        float v = red[0][t] + red[1][t] + red[2][t] + red[3][t] + boffA[t & 31];
        float v3 = v * v * v;
        hidl[t] = 0.5f * v * (1.f + tanhf(0.7978845608028654f * (v + 0.044715f * v3)));
    }
    __syncthreads();
    if (t < 12) {
        int b = t / 3, j = t % 3;
        float a = boffB[j];
        for (int o = 0; o < 32; ++o) a += WoffB[j * 32 + o] * hidl[b * 32 + o];
        float osc = (j == 0) ? 2.f : 8.f;
        float base = (j == 0) ? (zo * 2 + 0.5f) : ((j == 1) ? (ho * 8 + 3.5f) : (wo * 8 + 3.5f));
        coords[((size_t)b * L3_ + blk) * 3 + j] = base + tanhf(a) * osc;
    }
}

// ============================================================
// K8: trilinear sample kf/vf at coords -> ks/vs [b][200][32]
// ============================================================
__global__ __launch_bounds__(256) void k_trisample(const float* __restrict__ kf,
        const float* __restrict__ vf, const float* __restrict__ coords,
        float* __restrict__ ks, float* __restrict__ vs) {
    int t = threadIdx.x;
    int wv = blockIdx.x * 4 + (t >> 6);
    int b = wv / L3_, l = wv % L3_;
    int lane = t & 63;
    int c = lane & 31;
    const float* src = (lane < 32) ? kf : vf;
    float* dst = (lane < 32) ? ks : vs;
    const float* cp = coords + ((size_t)b * L3_ + l) * 3;
    float cz = cp[0], cy = cp[1], cx = cp[2];
    float z0 = floorf(cz), y0 = floorf(cy), x0 = floorf(cx);
    float wz = cz - z0, wy = cy - y0, wx = cx - x0;
    float acc = 0.f;
    #pragma unroll
    for (int dz = 0; dz < 2; ++dz) {
        float zf = z0 + (float)dz;
        if (zf < 0.f || zf > 3.f) continue;
        float wzf = dz ? wz : 1.f - wz;
        int zi = (int)zf;
        #pragma unroll
        for (int dy = 0; dy < 2; ++dy) {
            float yf = y0 + (float)dy;
            if (yf < 0.f || yf > 79.f) continue;
            float wyf = wzf * (dy ? wy : 1.f - wy);
            int yi = (int)yf;
            #pragma unroll
            for (int dx = 0; dx < 2; ++dx) {
                float xf = x0 + (float)dx;
                if (xf < 0.f || xf > 79.f) continue;
                float wgt = wyf * (dx ? wx : 1.f - wx);
                int xi = (int)xf;
                acc += wgt * src[((size_t)(b * 4 + zi) * HW_ + yi * W_ + xi) * 32 + c];
            }
        }
    }
    dst[((size_t)b * L3_ + l) * 32 + c] = acc;
}

// ============================================================
// K9: 25600-query x 200-key attention. Single-pass softmax.
// ============================================================
__global__ __launch_bounds__(256) void k_attn3d(const float* __restrict__ q3,
        const float* __restrict__ ks, const float* __restrict__ vs,
        float* __restrict__ o3) {
    __shared__ __align__(16) float ksl[L3_ * 32];
    __shared__ __align__(16) float vsl[L3_ * 32];
    int t = threadIdx.x;
    int b = blockIdx.x / 100;
    int chunk = blockIdx.x % 100;
    const float4* ksg = (const float4*)(ks + (size_t)b * L3_ * 32);
    const float4* vsg = (const float4*)(vs + (size_t)b * L3_ * 32);
    for (int d = t; d < L3_ * 8; d += 256) {
        ((float4*)ksl)[d] = ksg[d];
        ((float4*)vsl)[d] = vsg[d];
    }
    __syncthreads();
    int N = chunk * 256 + t;
    float q[32];
    const float4* qp = (const float4*)(q3 + ((size_t)b * NQ_ + N) * 32);
    #pragma unroll
    for (int i = 0; i < 8; ++i) ((float4*)q)[i] = qp[i];
    const float scale = 0.17677669529663687f;    // 32^-0.5
    float den = 0.f;
    float o[32];
    #pragma unroll
    for (int c = 0; c < 32; ++c) o[c] = 0.f;
    for (int l = 0; l < L3_; ++l) {
        const float4* kp = (const float4*)(ksl + l * 32);
        float s = 0.f;
        #pragma unroll
        for (int c4 = 0; c4 < 8; ++c4) {
            float4 kv = kp[c4];
            s += q[c4 * 4 + 0] * kv.x + q[c4 * 4 + 1] * kv.y + q[c4 * 4 + 2] * kv.z + q[c4 * 4 + 3] * kv.w;
        }
        float p = expf(s * scale);
        den += p;
        const float4* vp = (const float4*)(vsl + l * 32);
        #pragma unroll
        for (int c4 = 0; c4 < 8; ++c4) {
            float4 vv = vp[c4];
            o[c4 * 4 + 0] += p * vv.x; o[c4 * 4 + 1] += p * vv.y;
            o[c4 * 4 + 2] += p * vv.z; o[c4 * 4 + 3] += p * vv.w;
        }
    }
    float inv = 1.f / den;
    float* op = o3 + ((size_t)b * NQ_ + N) * 32;
    #pragma unroll
    for (int c = 0; c < 32; ++c) op[c] = o[c] * inv;
}

// ============================================================
// K10: tiled GEMM  out += r1 * (o3 @ W_out3^T + bias)
// ============================================================
__global__ __launch_bounds__(256) void k_final(const float* __restrict__ o3,
        const float* __restrict__ W, const float* __restrict__ bias,
        const float* __restrict__ r1p, float* __restrict__ out) {
    __shared__ float o3T[32 * 128];     // [k][row]
    __shared__ float WT[32 * 260];      // [k][c]
    int t = threadIdx.x;
    int R0 = blockIdx.x * 128;
    {
        int row = t >> 1, k0 = (t & 1) * 16;
        int R = R0 + row;
        int b = R & 3, N = R >> 2;
        const float* src = o3 + ((size_t)b * NQ_ + N) * 32 + k0;
        #pragma unroll
        for (int j = 0; j < 16; ++j) o3T[(k0 + j) * 128 + row] = src[j];
    }
    for (int d = t; d < 8192; d += 256) {
        int c = d >> 5, k = d & 31;
        WT[k * 260 + c] = W[d];
    }
    __syncthreads();
    int tc = t & 15;
    int tr = t >> 4;
    int r0 = tr * 8;
    float acc[8][16];
    #pragma unroll
    for (int i = 0; i < 8; ++i)
        #pragma unroll
        for (int j = 0; j < 16; ++j) acc[i][j] = 0.f;
    #pragma unroll 1
    for (int k = 0; k < 32; ++k) {
        float a[8];
        *(float4*)&a[0] = *(const float4*)&o3T[k * 128 + r0];
        *(float4*)&a[4] = *(const float4*)&o3T[k * 128 + r0 + 4];
        float wv[16];
        #pragma unroll
        for (int ci = 0; ci < 16; ++ci) wv[ci] = WT[k * 260 + tc + 16 * ci];
        #pragma unroll
        for (int i = 0; i < 8; ++i)
            #pragma unroll
            for (int j = 0; j < 16; ++j) acc[i][j] += a[i] * wv[j];
    }
    float r1 = r1p[0];
    float bs[16];
    #pragma unroll
    for (int ci = 0; ci < 16; ++ci) bs[ci] = bias[tc + 16 * ci];
    #pragma unroll 1
    for (int i = 0; i < 8; ++i) {
        size_t rowbase = (size_t)(R0 + r0 + i) * 256;
        #pragma unroll
        for (int j = 0; j < 16; ++j) {
            size_t oi = rowbase + tc + 16 * j;
            out[oi] = r1 * (acc[i][j] + bs[j]) + out[oi];
        }
    }
}

// ============================================================
extern "C" void kernel_launch(void* const* d_in, const int* in_sizes, int n_in,
                              void* d_out, int out_size, void* d_ws, size_t ws_size,
                              hipStream_t stream) {
    (void)in_sizes; (void)n_in; (void)out_size; (void)ws_size;
    const float* x      = (const float*)d_in[0];
    const float* W_qkv  = (const float*)d_in[1];
    const float* b_qkv  = (const float*)d_in[2];
    const float* W_fc   = (const float*)d_in[3];
    const float* b_fc   = (const float*)d_in[4];
    const float* W_doff = (const float*)d_in[5];
    const float* b_doff = (const float*)d_in[6];
    const float* W_dep  = (const float*)d_in[7];
    const float* b_dep  = (const float*)d_in[8];
    const float* W_st   = (const float*)d_in[9];
    const float* b_st   = (const float*)d_in[10];
    const float* W_off2d= (const float*)d_in[11];
    const float* b_off2d= (const float*)d_in[12];
    const float* W_attw = (const float*)d_in[13];
    const float* b_attw = (const float*)d_in[14];
    const float* W_val  = (const float*)d_in[15];
    const float* b_val  = (const float*)d_in[16];
    const float* W_out2d= (const float*)d_in[17];
    const float* b_out2d= (const float*)d_in[18];
    const float* W_q3   = (const float*)d_in[19];
    const float* b_q3   = (const float*)d_in[20];
    const float* W_k3   = (const float*)d_in[21];
    const float* b_k3   = (const float*)d_in[22];
    const float* W_v3   = (const float*)d_in[23];
    const float* b_v3   = (const float*)d_in[24];
    const float* W_offA = (const float*)d_in[25];
    const float* b_offA = (const float*)d_in[26];
    const float* W_offB = (const float*)d_in[27];
    const float* b_offB = (const float*)d_in[28];
    const float* W_out3 = (const float*)d_in[29];
    const float* b_out3 = (const float*)d_in[30];
    const float* rate1  = (const float*)d_in[31];
    const float* rate2  = (const float*)d_in[32];

    float* ws  = (float*)d_ws;
    float* out = (float*)d_out;
    float* qhp = ws + WS_QH;
    float* khp = ws + WS_KH;
    float* fn2 = ws + WS_FIN2;
    float* off = ws + WS_OFF;
    float* v2  = ws + WS_V2;
    float* a2  = ws + WS_A2;
    float* q3  = ws + WS_Q3;
    float* kf  = ws + WS_KF;
    float* vf  = ws + WS_VF;
    float* crd = ws + WS_CRD;
    float* ks  = ws + WS_KS;
    float* vs  = ws + WS_VS;
    float* o3w = ws + WS_O3;

    k_qkv      <<<3200,   256, 0, stream>>>(x, W_qkv, b_qkv, qhp, khp);
    k_fin_v2   <<<400,    256, 0, stream>>>(qhp, khp, W_fc, b_fc, W_val, b_val, fn2, v2);
    k_offconv  <<<1600,   256, 0, stream>>>(fn2, W_doff, b_doff, off);
    k_depst    <<<1600,   256, 0, stream>>>(fn2, off, W_dep, b_dep, W_st, b_st, rate2, out);
    k_attn2d   <<<1600,   256, 0, stream>>>(qhp, v2, W_off2d, b_off2d, W_attw, b_attw, W_out2d, b_out2d, a2);
    k_qkv3     <<<1600,   256, 0, stream>>>(a2, W_q3, b_q3, W_k3, b_k3, W_v3, b_v3, q3, kf, vf);
    k_offs3d   <<<200,    256, 0, stream>>>(q3, W_offA, b_offA, W_offB, b_offB, crd);
    k_trisample<<<200,    256, 0, stream>>>(kf, vf, crd, ks, vs);
    k_attn3d   <<<400,    256, 0, stream>>>(q3, ks, vs, o3w);
    k_final    <<<800,    256, 0, stream>>>(o3w, W_out3, b_out3, rate1, out);
}

// Round 9
// 877.883 us; speedup vs baseline: 1.1221x; 1.1221x over previous
//
#include <hip/hip_runtime.h>
#include <math.h>

// ---- problem constants ----
#define B_     4
#define NIMG_  4
#define H_     80
#define W_     80
#define C_     256
#define NH_    8
#define HW_    6400     // H*W
#define NQ_    25600    // NIMG*H*W
#define NPIX_  102400   // B*NQ
#define L3_    200      // 2*10*10 sample points

// ---- workspace layout (float offsets), regions reused across stages ----
// fin2: g-interleaved padded conv-feature layout [bn][hw][48]
// lifetimes: qh K1->K5, kh K1->K2, v2 K2->K5, fin2 K2->K4, off K3->K4,
// a2 K5->K6, q3 K6->K9, kf/vf K6->K8, crd/ks/vs K7->K9, o3 K9->K10.
#define WS_QH   0u
#define WS_KH   3276800u
#define WS_V2   6553600u
#define WS_FIN2 9830400u
#define WS_OFF  3276800u
#define WS_A2   9830400u
#define WS_Q3   0u
#define WS_KF   3276800u
#define WS_VF   6553600u
#define WS_CRD  9830400u
#define WS_KS   9832800u
#define WS_VS   9858400u
#define WS_O3   3276800u

// branchless bilinear 9-ch sample from a g-slice of fin2 (48-float records)
__device__ __forceinline__ void bilin9(const float* __restrict__ finb,
        float py, float px, float* __restrict__ s) {
    float y0f = floorf(py), x0f = floorf(px);
    float wy = py - y0f, wx = px - x0f;
    float wy0 = 1.f - wy, wx0 = 1.f - wx;
    float vy0 = (y0f >= 0.f && y0f <= 79.f) ? 1.f : 0.f;
    float vy1 = (y0f >= -1.f && y0f <= 78.f) ? 1.f : 0.f;
    float vx0 = (x0f >= 0.f && x0f <= 79.f) ? 1.f : 0.f;
    float vx1 = (x0f >= -1.f && x0f <= 78.f) ? 1.f : 0.f;
    int yi0 = (int)fminf(fmaxf(y0f, 0.f), 79.f);
    int yi1 = (int)fminf(fmaxf(y0f + 1.f, 0.f), 79.f);
    int xi0 = (int)fminf(fmaxf(x0f, 0.f), 79.f);
    int xi1 = (int)fminf(fmaxf(x0f + 1.f, 0.f), 79.f);
    float w00 = wy0 * wx0 * vy0 * vx0;
    float w01 = wy0 * wx  * vy0 * vx1;
    float w10 = wy  * wx0 * vy1 * vx0;
    float w11 = wy  * wx  * vy1 * vx1;
    const float4* c00 = (const float4*)(finb + (size_t)(yi0 * W_ + xi0) * 48);
    const float4* c01 = (const float4*)(finb + (size_t)(yi0 * W_ + xi1) * 48);
    const float4* c10 = (const float4*)(finb + (size_t)(yi1 * W_ + xi0) * 48);
    const float4* c11 = (const float4*)(finb + (size_t)(yi1 * W_ + xi1) * 48);
    {
        float4 p0 = c00[0], p1 = c00[1], p2 = c00[2];
        s[0] = w00 * p0.x; s[1] = w00 * p0.y; s[2] = w00 * p0.z; s[3] = w00 * p0.w;
        s[4] = w00 * p1.x; s[5] = w00 * p1.y; s[6] = w00 * p1.z; s[7] = w00 * p1.w;
        s[8] = w00 * p2.x;
    }
    {
        float4 p0 = c01[0], p1 = c01[1], p2 = c01[2];
        s[0] += w01 * p0.x; s[1] += w01 * p0.y; s[2] += w01 * p0.z; s[3] += w01 * p0.w;
        s[4] += w01 * p1.x; s[5] += w01 * p1.y; s[6] += w01 * p1.z; s[7] += w01 * p1.w;
        s[8] += w01 * p2.x;
    }
    {
        float4 p0 = c10[0], p1 = c10[1], p2 = c10[2];
        s[0] += w10 * p0.x; s[1] += w10 * p0.y; s[2] += w10 * p0.z; s[3] += w10 * p0.w;
        s[4] += w10 * p1.x; s[5] += w10 * p1.y; s[6] += w10 * p1.z; s[7] += w10 * p1.w;
        s[8] += w10 * p2.x;
    }
    {
        float4 p0 = c11[0], p1 = c11[1], p2 = c11[2];
        s[0] += w11 * p0.x; s[1] += w11 * p0.y; s[2] += w11 * p0.z; s[3] += w11 * p0.w;
        s[4] += w11 * p1.x; s[5] += w11 * p1.y; s[6] += w11 * p1.z; s[7] += w11 * p1.w;
        s[8] += w11 * p2.x;
    }
}

// ============================================================
// K1: qh/kh = xb @ W_qkv + b_qkv, split into the two 32-ch halves
// ============================================================
__global__ __launch_bounds__(256) void k_qkv(const float* __restrict__ x,
        const float* __restrict__ Wq, const float* __restrict__ bq,
        float* __restrict__ qh, float* __restrict__ kh) {
    __shared__ __align__(16) float xs[32][256];
    int t = threadIdx.x;
    int row0 = blockIdx.x * 32;
    for (int it = 0; it < 8; ++it) {
        int idx = t + it * 256;
        int r = idx >> 6;
        int f4 = idx & 63;
        int row = row0 + r;
        int b = row / NQ_, n = row % NQ_;
        const float4* src = (const float4*)(x + ((size_t)n * B_ + b) * C_);
        ((float4*)&xs[r][0])[f4] = src[f4];
    }
    __syncthreads();
    int j = t & 63;
    int rbase = (t >> 6) * 8;
    float acc[8];
    #pragma unroll
    for (int r = 0; r < 8; ++r) acc[r] = 0.f;
    for (int c4 = 0; c4 < 64; ++c4) {
        float w0 = Wq[(c4 * 4 + 0) * 64 + j];
        float w1 = Wq[(c4 * 4 + 1) * 64 + j];
        float w2 = Wq[(c4 * 4 + 2) * 64 + j];
        float w3 = Wq[(c4 * 4 + 3) * 64 + j];
        #pragma unroll
        for (int r = 0; r < 8; ++r) {
            float4 xv = ((const float4*)&xs[rbase + r][0])[c4];
            acc[r] += xv.x * w0 + xv.y * w1 + xv.z * w2 + xv.w * w3;
        }
    }
    float bias = bq[j];
    #pragma unroll
    for (int r = 0; r < 8; ++r) {
        int row = row0 + rbase + r;
        float vres = acc[r] + bias;
        if (j < 32) qh[(size_t)row * 32 + j] = vres;
        else        kh[(size_t)row * 32 + (j - 32)] = vres;
    }
}

// ============================================================
// K2: fin2 (g-interleaved 48-float records) + v2 (32ch) per pixel.
// ============================================================
__global__ __launch_bounds__(256) void k_fin_v2(const float* __restrict__ qh,
        const float* __restrict__ kh,
        const float* __restrict__ Wfc, const float* __restrict__ bfc,
        const float* __restrict__ Wval, const float* __restrict__ bval,
        float* __restrict__ fin2, float* __restrict__ v2) {
    __shared__ float WvalL[1024], WfcL[144], bfcL[9], bvalL[32];
    int t = threadIdx.x;
    for (int d = t; d < 1024; d += 256) WvalL[d] = Wval[d];
    if (t < 144) WfcL[t] = Wfc[t];
    if (t >= 160 && t < 169) bfcL[t - 160] = bfc[t - 160];
    if (t >= 192 && t < 224) bvalL[t - 192] = bval[t - 192];
    __syncthreads();
    int P = blockIdx.x * 256 + t;
    int b = P / NQ_, nq = P % NQ_;
    int n = nq / HW_, hw = nq % HW_;
    int bn = b * NIMG_ + n;
    float q[64];
    const float4* qp = (const float4*)(qh + (size_t)P * 32);
    const float4* kp = (const float4*)(kh + (size_t)P * 32);
    #pragma unroll
    for (int i = 0; i < 8; ++i) ((float4*)q)[i] = qp[i];
    #pragma unroll
    for (int i = 0; i < 8; ++i) ((float4*)q)[8 + i] = kp[i];
    float fo[36];
    #pragma unroll
    for (int k = 0; k < 4; ++k)
        #pragma unroll
        for (int o = 0; o < 9; ++o) fo[k * 9 + o] = bfcL[o];
    for (int c = 0; c < 16; ++c) {
        #pragma unroll
        for (int o = 0; o < 9; ++o) {
            float wv = WfcL[o * 16 + c];
            #pragma unroll
            for (int k = 0; k < 4; ++k) fo[k * 9 + o] += wv * q[c * 4 + k];
        }
    }
    float* fp = fin2 + ((size_t)bn * HW_ + hw) * 48;
    #pragma unroll
    for (int g = 0; g < 4; ++g) {
        ((float4*)fp)[g * 3 + 0] = make_float4(fo[g * 9 + 0], fo[g * 9 + 1], fo[g * 9 + 2], fo[g * 9 + 3]);
        ((float4*)fp)[g * 3 + 1] = make_float4(fo[g * 9 + 4], fo[g * 9 + 5], fo[g * 9 + 6], fo[g * 9 + 7]);
        ((float4*)fp)[g * 3 + 2] = make_float4(fo[g * 9 + 8], 0.f, 0.f, 0.f);
    }
    float vo[32];
    #pragma unroll
    for (int j = 0; j < 32; ++j) vo[j] = bvalL[j];
    for (int c = 0; c < 32; ++c) {
        float qc = q[32 + c];
        #pragma unroll
        for (int j = 0; j < 32; ++j) vo[j] += qc * WvalL[c * 32 + j];
    }
    float* vp = v2 + ((size_t)bn * HW_ + hw) * 32;
    #pragma unroll
    for (int i = 0; i < 8; ++i) ((float4*)vp)[i] = ((float4*)vo)[i];
}

// ============================================================
// K3 (R4 version): off = conv2d(fin, W_doff, pad 1) + b_doff
// 1 px/thread; fin2 read as one contiguous 12 x float4 stream/tap.
// (R5's 2px and R8's 4-lane variants both regressed -- reverted.)
// ============================================================
__global__ __launch_bounds__(256) void k_offconv(const float* __restrict__ fin2,
        const float* __restrict__ Wdoff, const float* __restrict__ bdoff,
        float* __restrict__ off) {
    __shared__ float Wl[5832];  // [tap][c36][o18]
    int t = threadIdx.x;
    for (int d = t; d < 5832; d += 256) {
        int tap = d / 648, r = d % 648, c = r / 18, o = r % 18;
        Wl[d] = Wdoff[(o * 36 + c) * 9 + tap];
    }
    __syncthreads();
    int P = blockIdx.x * 256 + t;
    int bn = P / HW_, hw = P % HW_;
    int h = hw / W_, w = hw % W_;
    float acc[18];
    #pragma unroll
    for (int o = 0; o < 18; ++o) acc[o] = bdoff[o];
    for (int ky = 0; ky < 3; ++ky) {
        int hh = h + ky - 1;
        if (hh < 0 || hh >= H_) continue;
        for (int kx = 0; kx < 3; ++kx) {
            int ww = w + kx - 1;
            if (ww < 0 || ww >= W_) continue;
            int sp = hh * W_ + ww;
            const float4* base = (const float4*)(fin2 + ((size_t)bn * HW_ + sp) * 48);
            const float* wl = Wl + (ky * 3 + kx) * 648;
            #pragma unroll
            for (int g = 0; g < 4; ++g) {
                float4 p0 = base[g * 3 + 0], p1 = base[g * 3 + 1], p2 = base[g * 3 + 2];
                float vals[9] = {p0.x, p0.y, p0.z, p0.w, p1.x, p1.y, p1.z, p1.w, p2.x};
                #pragma unroll
                for (int idx = 0; idx < 9; ++idx) {
                    const float* w0 = wl + (g * 9 + idx) * 18;
                    float vv = vals[idx];
                    #pragma unroll
                    for (int o = 0; o < 18; ++o) acc[o] += vv * w0[o];
                }
            }
        }
    }
    float* op = off + (size_t)P * 18;
    #pragma unroll
    for (int o = 0; o < 18; ++o) op[o] = acc[o];
}

// ============================================================
// K4 (R4 version, best measured 148us): 1 px/thread, per-g weights
// in LDS (broadcast reads), fin2 48B records, XCD chunk swizzle.
// R5/R6/R7 attempts (2px, scalar weights) all neutral-or-worse:
// kernel is latency-pinned at ~150us at its structural grain.
// ============================================================
__global__ __launch_bounds__(256, 4) void k_depst(const float* __restrict__ fin2,
        const float* __restrict__ off, const float* __restrict__ Wdep,
        const float* __restrict__ bdep, const float* __restrict__ Wst,
        const float* __restrict__ bst, const float* __restrict__ rate2p,
        float* __restrict__ out) {
    __shared__ __align__(16) float wdepL[2268];   // [k][i][o28]
    __shared__ __align__(16) float wstL[1728];    // [i][o64]
    __shared__ float bdepL[27];
    __shared__ float bstL[64];
    int t = threadIdx.x;
    int bx = blockIdx.x;
    int u = (bx & 7) * 200 + (bx >> 3);   // bijective, 1600 % 8 == 0
    int chunk = u >> 2, g = u & 3;
    for (int d = t; d < 2268; d += 256) {
        int k = d / 252, r2 = d % 252;
        int i = r2 / 28, o = r2 % 28;
        wdepL[d] = (o < 27) ? Wdep[(size_t)(g * 27 + o) * 81 + i * 9 + k] : 0.f;
    }
    for (int d = t; d < 1728; d += 256) {
        int i = d >> 6, o = d & 63;
        wstL[d] = Wst[g * 1728 + o * 27 + i];
    }
    if (t < 27) bdepL[t] = bdep[g * 27 + t];
    if (t >= 32 && t < 96) bstL[t - 32] = bst[g * 64 + (t - 32)];
    __syncthreads();
    int P = chunk * 256 + t;
    int bn = P / HW_, hw = P % HW_;
    int h = hw / W_, w = hw % W_;
    int b = bn >> 2, n = bn & 3;
    const float* finb = fin2 + (size_t)bn * (HW_ * 48) + g * 12;
    float2 offs[9];
    {
        const float2* op2 = (const float2*)(off + (size_t)P * 18);
        #pragma unroll
        for (int k = 0; k < 9; ++k) offs[k] = op2[k];
    }
    float acc[27];
    #pragma unroll
    for (int o = 0; o < 27; ++o) acc[o] = 0.f;
    float hf = (float)h, wf = (float)w;
    #pragma unroll 1
    for (int k = 0; k < 9; ++k) {
        float py = hf + (float)(k / 3 - 1) + offs[k].x;
        float px = wf + (float)(k % 3 - 1) + offs[k].y;
        float s[9];
        bilin9(finb, py, px, s);
        const float* wk = wdepL + k * 252;
        #pragma unroll
        for (int i = 0; i < 9; ++i) {
            float si = s[i];
            const float4* rw = (const float4*)(wk + i * 28);
            float4 q0 = rw[0], q1 = rw[1], q2 = rw[2], q3v = rw[3];
            float4 q4 = rw[4], q5 = rw[5], q6 = rw[6];
            acc[0]  += si * q0.x;  acc[1]  += si * q0.y;  acc[2]  += si * q0.z;  acc[3]  += si * q0.w;
            acc[4]  += si * q1.x;  acc[5]  += si * q1.y;  acc[6]  += si * q1.z;  acc[7]  += si * q1.w;
            acc[8]  += si * q2.x;  acc[9]  += si * q2.y;  acc[10] += si * q2.z;  acc[11] += si * q2.w;
            acc[12] += si * q3v.x; acc[13] += si * q3v.y; acc[14] += si * q3v.z; acc[15] += si * q3v.w;
            acc[16] += si * q4.x;  acc[17] += si * q4.y;  acc[18] += si * q4.z;  acc[19] += si * q4.w;
            acc[20] += si * q5.x;  acc[21] += si * q5.y;  acc[22] += si * q5.z;  acc[23] += si * q5.w;
            acc[24] += si * q6.x;  acc[25] += si * q6.y;  acc[26] += si * q6.z;
        }
    }
    #pragma unroll
    for (int i = 0; i < 27; ++i) acc[i] += bdepL[i];
    float r2v = rate2p[0];
    float* ob = out + ((size_t)(n * HW_ + hw) * B_ + b) * C_ + g * 64;
    #pragma unroll 1
    for (int half = 0; half < 2; ++half) {
        float ro[32];
        #pragma unroll
        for (int o = 0; o < 32; ++o) ro[o] = bstL[half * 32 + o];
        #pragma unroll
        for (int i = 0; i < 27; ++i) {
            float ai = acc[i];
            const float4* rw = (const float4*)(wstL + i * 64 + half * 32);
            #pragma unroll
            for (int j = 0; j < 8; ++j) {
                float4 wv = rw[j];
                ro[j * 4 + 0] += ai * wv.x;
                ro[j * 4 + 1] += ai * wv.y;
                ro[j * 4 + 2] += ai * wv.z;
                ro[j * 4 + 3] += ai * wv.w;
            }
        }
        float4* obv = (float4*)(ob + half * 32);
        #pragma unroll
        for (int o4 = 0; o4 < 8; ++o4)
            obv[o4] = make_float4(r2v * ro[o4 * 4 + 0], r2v * ro[o4 * 4 + 1],
                                  r2v * ro[o4 * 4 + 2], r2v * ro[o4 * 4 + 3]);
    }
}

// ============================================================
// K5 (R4 version): 2D deformable attention, 1 px/thread, weights
// in LDS. (R8's 4-lane head-split regressed -- staging overhead and
// redundant per-pixel loads outweighed the latency win; reverted.)
// ============================================================
__global__ __launch_bounds__(256) void k_attn2d(const float* __restrict__ qh,
        const float* __restrict__ v2,
        const float* __restrict__ Woff, const float* __restrict__ boff,
        const float* __restrict__ Watt, const float* __restrict__ batt,
        const float* __restrict__ Wout, const float* __restrict__ bout,
        float* __restrict__ a2) {
    __shared__ float WoffL[2048], WattL[1024], WoutL[1024];
    __shared__ float boffL[64], battL[32], boutL[32];
    int t = threadIdx.x;
    for (int d = t; d < 2048; d += 256) WoffL[d] = Woff[d];
    for (int d = t; d < 1024; d += 256) { WattL[d] = Watt[d]; WoutL[d] = Wout[d]; }
    if (t < 64) boffL[t] = boff[t];
    else if (t < 96) battL[t - 64] = batt[t - 64];
    else if (t < 128) boutL[t - 96] = bout[t - 96];
    __syncthreads();
    int P = blockIdx.x * 256 + t;
    int b = P / NQ_, nq = P % NQ_;
    int n = nq / HW_, hw = nq % HW_;
    int h = hw / W_, w = hw % W_;
    int bn = b * NIMG_ + n;
    float q[32];
    const float4* qp = (const float4*)(qh + (size_t)P * 32);
    #pragma unroll
    for (int i = 0; i < 8; ++i) ((float4*)q)[i] = qp[i];
    const float* vbase = v2 + (size_t)bn * HW_ * 32;
    float a2v[32];
    #pragma unroll
    for (int i = 0; i < 32; ++i) a2v[i] = 0.f;
    for (int nh = 0; nh < 8; ++nh) {
        float t0 = battL[nh * 4 + 0], t1 = battL[nh * 4 + 1];
        float t2 = battL[nh * 4 + 2], t3 = battL[nh * 4 + 3];
        for (int c = 0; c < 32; ++c) {
            float qc = q[c];
            const float* wr = WattL + c * 32 + nh * 4;
            t0 += qc * wr[0]; t1 += qc * wr[1]; t2 += qc * wr[2]; t3 += qc * wr[3];
        }
        float m = fmaxf(fmaxf(t0, t1), fmaxf(t2, t3));
        float e0 = expf(t0 - m), e1 = expf(t1 - m), e2 = expf(t2 - m), e3 = expf(t3 - m);
        float inv = 1.f / (e0 + e1 + e2 + e3);
        float pk[4] = {e0 * inv, e1 * inv, e2 * inv, e3 * inv};
        #pragma unroll
        for (int kk = 0; kk < 4; ++kk) {
            int j0 = nh * 8 + kk * 2;
            float ox = boffL[j0], oy = boffL[j0 + 1];
            for (int c = 0; c < 32; ++c) {
                float qc = q[c];
                ox += qc * WoffL[c * 64 + j0];
                oy += qc * WoffL[c * 64 + j0 + 1];
            }
            float ppx = (float)w + ox * (79.f / 80.f);
            float ppy = (float)h + oy * (79.f / 80.f);
            float x0 = floorf(ppx), y0 = floorf(ppy);
            float wx = ppx - x0, wy = ppy - y0;
            float s0 = 0.f, s1 = 0.f, s2 = 0.f, s3 = 0.f;
            #pragma unroll
            for (int cy = 0; cy < 2; ++cy) {
                float yf = y0 + (float)cy;
                if (yf < 0.f || yf > 79.f) continue;
                float wyf = cy ? wy : 1.f - wy;
                int yi = (int)yf;
                #pragma unroll
                for (int cx = 0; cx < 2; ++cx) {
                    float xf = x0 + (float)cx;
                    if (xf < 0.f || xf > 79.f) continue;
                    float wgt = wyf * (cx ? wx : 1.f - wx);
                    int xi = (int)xf;
                    float4 vv = *(const float4*)(vbase + ((size_t)yi * W_ + xi) * 32 + nh * 4);
                    s0 += wgt * vv.x; s1 += wgt * vv.y; s2 += wgt * vv.z; s3 += wgt * vv.w;
                }
            }
            float p = pk[kk];
            a2v[nh * 4 + 0] += p * s0; a2v[nh * 4 + 1] += p * s1;
            a2v[nh * 4 + 2] += p * s2; a2v[nh * 4 + 3] += p * s3;
        }
    }
    float ro[32];
    #pragma unroll
    for (int o = 0; o < 32; ++o) ro[o] = boutL[o];
    for (int c = 0; c < 32; ++c) {
        float ac = a2v[c];
        const float* wr = WoutL + c * 32;
        #pragma unroll
        for (int o = 0; o < 32; ++o) ro[o] += ac * wr[o];
    }
    float* op = a2 + ((size_t)bn * HW_ + hw) * 32;
    #pragma unroll
    for (int i = 0; i < 8; ++i) ((float4*)op)[i] = ((float4*)ro)[i];
}

// ============================================================
// K6 (R4 version): q3/kf/vf projections, 1 px/thread, weights in LDS.
// ============================================================
__global__ __launch_bounds__(256) void k_qkv3(const float* __restrict__ a2,
        const float* __restrict__ Wq3, const float* __restrict__ bq3,
        const float* __restrict__ Wk3, const float* __restrict__ bk3,
        const float* __restrict__ Wv3, const float* __restrict__ bv3,
        float* __restrict__ q3, float* __restrict__ kf, float* __restrict__ vf) {
    __shared__ float Wq3L[1024], Wk3L[1024], Wv3L[1024];
    __shared__ float bq3L[32], bk3L[32], bv3L[32];
    int t = threadIdx.x;
    for (int d = t; d < 1024; d += 256) {
        Wq3L[d] = Wq3[d]; Wk3L[d] = Wk3[d]; Wv3L[d] = Wv3[d];
    }
    if (t < 32) { bq3L[t] = bq3[t]; bk3L[t] = bk3[t]; bv3L[t] = bv3[t]; }
    __syncthreads();
    int idx = blockIdx.x * 256 + t;
    int bn = idx / HW_, hw = idx % HW_;
    int b = bn >> 2, n = bn & 3;
    int ns = (n == 0) ? 0 : n - 1;
    const float* src = a2 + ((size_t)(b * 4 + ns) * HW_ + hw) * 32;
    float v[32];
    #pragma unroll
    for (int i = 0; i < 8; ++i) ((float4*)v)[i] = ((const float4*)src)[i];
    float oq[32], ok[32], ov[32];
    #pragma unroll
    for (int o = 0; o < 32; ++o) {
        float aq = bq3L[o], ak = bk3L[o], av = bv3L[o];
        #pragma unroll
        for (int c = 0; c < 32; ++c) {
            aq += Wq3L[o * 32 + c] * v[c];
            ak += Wk3L[o * 32 + c] * v[c];
            av += Wv3L[o * 32 + c] * v[c];
        }
        oq[o] = aq; ok[o] = ak; ov[o] = av;
    }
    float* qo = q3 + (size_t)idx * 32;
    float* ko = kf + (size_t)idx * 32;
    float* vo = vf + (size_t)idx * 32;
    #pragma unroll
    for (int i = 0; i < 8; ++i) {
        ((float4*)qo)[i] = ((float4*)oq)[i];
        ((float4*)ko)[i] = ((float4*)ok)[i];
        ((float4*)vo)[i] = ((float4*)ov)[i];
    }
}

// ============================================================
// K7: strided conv3d (W_offA) + gelu + W_offB + tanh*OSC -> sample coords
// ============================================================
__global__ __launch_bounds__(256) void k_offs3d(const float* __restrict__ q3,
        const float* __restrict__ WoffA, const float* __restrict__ boffA,
        const float* __restrict__ WoffB, const float* __restrict__ boffB,
        float* __restrict__ coords) {
    __shared__ float red[4][128];
    __shared__ float hidl[128];
    int t = threadIdx.x;
    int blk = blockIdx.x;
    int zo = blk / 100, r = blk % 100, ho = r / 10, wo = r % 10;
    float acc[4][32];
    #pragma unroll
    for (int b = 0; b < 4; ++b)
        #pragma unroll
        for (int o = 0; o < 32; ++o) acc[b][o] = 0.f;
    for (int tap = t; tap < 400; tap += 256) {
        int kz = tap / 100, r2 = tap % 100, ky = r2 / 10, kx = r2 % 10;
        int zi = zo * 2 + kz - 1, hi = ho * 8 + ky - 1, wi = wo * 8 + kx - 1;
        if (zi < 0 || zi >= NIMG_ || hi < 0 || hi >= H_ || wi < 0 || wi >= W_) continue;
        const float* wb = WoffA + tap;
        int sp = hi * W_ + wi;
        for (int c = 0; c < 32; ++c) {
            float vb[4];
            #pragma unroll
            for (int b = 0; b < 4; ++b)
                vb[b] = q3[((size_t)(b * 4 + zi) * HW_ + sp) * 32 + c];
            #pragma unroll
            for (int o = 0; o < 32; ++o) {
                float wv = wb[(o * 32 + c) * 400];
                #pragma unroll
                for (int b = 0; b < 4; ++b) acc[b][o] += vb[b] * wv;
            }
        }
    }
    #pragma unroll
    for (int b = 0; b < 4; ++b)
        #pragma unroll
        for (int o = 0; o < 32; ++o)
            for (int sh = 32; sh >= 1; sh >>= 1)
                acc[b][o] += __shfl_xor(acc[b][o], sh);
    int lane = t & 63, wv = t >> 6;
    if (lane == 0)
        for (int b = 0; b < 4; ++b)
            for (int o = 0; o < 32; ++o) red[wv][b * 32 + o] = acc[b][o];
    __syncthreads();
    if (t < 128) {
        float v = red[0][t] + red[1][t] + red[2][t] + red[3][t] + boffA[t & 31];
        float v3 = v * v * v;
        hidl[t] = 0.5f * v * (1.f + tanhf(0.7978845608028654f * (v + 0.044715f * v3)));
    }
    __syncthreads();
    if (t < 12) {
        int b = t / 3, j = t % 3;
        float a = boffB[j];
        for (int o = 0; o < 32; ++o) a += WoffB[j * 32 + o] * hidl[b * 32 + o];
        float osc = (j == 0) ? 2.f : 8.f;
        float base = (j == 0) ? (zo * 2 + 0.5f) : ((j == 1) ? (ho * 8 + 3.5f) : (wo * 8 + 3.5f));
        coords[((size_t)b * L3_ + blk) * 3 + j] = base + tanhf(a) * osc;
    }
}

// ============================================================
// K8: trilinear sample kf/vf at coords -> ks/vs [b][200][32]
// ============================================================
__global__ __launch_bounds__(256) void k_trisample(const float* __restrict__ kf,
        const float* __restrict__ vf, const float* __restrict__ coords,
        float* __restrict__ ks, float* __restrict__ vs) {
    int t = threadIdx.x;
    int wv = blockIdx.x * 4 + (t >> 6);
    int b = wv / L3_, l = wv % L3_;
    int lane = t & 63;
    int c = lane & 31;
    const float* src = (lane < 32) ? kf : vf;
    float* dst = (lane < 32) ? ks : vs;
    const float* cp = coords + ((size_t)b * L3_ + l) * 3;
    float cz = cp[0], cy = cp[1], cx = cp[2];
    float z0 = floorf(cz), y0 = floorf(cy), x0 = floorf(cx);
    float wz = cz - z0, wy = cy - y0, wx = cx - x0;
    float acc = 0.f;
    #pragma unroll
    for (int dz = 0; dz < 2; ++dz) {
        float zf = z0 + (float)dz;
        if (zf < 0.f || zf > 3.f) continue;
        float wzf = dz ? wz : 1.f - wz;
        int zi = (int)zf;
        #pragma unroll
        for (int dy = 0; dy < 2; ++dy) {
            float yf = y0 + (float)dy;
            if (yf < 0.f || yf > 79.f) continue;
            float wyf = wzf * (dy ? wy : 1.f - wy);
            int yi = (int)yf;
            #pragma unroll
            for (int dx = 0; dx < 2; ++dx) {
                float xf = x0 + (float)dx;
                if (xf < 0.f || xf > 79.f) continue;
                float wgt = wyf * (dx ? wx : 1.f - wx);
                int xi = (int)xf;
                acc += wgt * src[((size_t)(b * 4 + zi) * HW_ + yi * W_ + xi) * 32 + c];
            }
        }
    }
    dst[((size_t)b * L3_ + l) * 32 + c] = acc;
}

// ============================================================
// K9: 25600-query x 200-key attention. Single-pass softmax.
// ============================================================
__global__ __launch_bounds__(256) void k_attn3d(const float* __restrict__ q3,
        const float* __restrict__ ks, const float* __restrict__ vs,
        float* __restrict__ o3) {
    __shared__ __align__(16) float ksl[L3_ * 32];
    __shared__ __align__(16) float vsl[L3_ * 32];
    int t = threadIdx.x;
    int b = blockIdx.x / 100;
    int chunk = blockIdx.x % 100;
    const float4* ksg = (const float4*)(ks + (size_t)b * L3_ * 32);
    const float4* vsg = (const float4*)(vs + (size_t)b * L3_ * 32);
    for (int d = t; d < L3_ * 8; d += 256) {
        ((float4*)ksl)[d] = ksg[d];
        ((float4*)vsl)[d] = vsg[d];
    }
    __syncthreads();
    int N = chunk * 256 + t;
    float q[32];
    const float4* qp = (const float4*)(q3 + ((size_t)b * NQ_ + N) * 32);
    #pragma unroll
    for (int i = 0; i < 8; ++i) ((float4*)q)[i] = qp[i];
    const float scale = 0.17677669529663687f;    // 32^-0.5
    float den = 0.f;
    float o[32];
    #pragma unroll
    for (int c = 0; c < 32; ++c) o[c] = 0.f;
    for (int l = 0; l < L3_; ++l) {
        const float4* kp = (const float4*)(ksl + l * 32);
        float s = 0.f;
        #pragma unroll
        for (int c4 = 0; c4 < 8; ++c4) {
            float4 kv = kp[c4];
            s += q[c4 * 4 + 0] * kv.x + q[c4 * 4 + 1] * kv.y + q[c4 * 4 + 2] * kv.z + q[c4 * 4 + 3] * kv.w;
        }
        float p = expf(s * scale);
        den += p;
        const float4* vp = (const float4*)(vsl + l * 32);
        #pragma unroll
        for (int c4 = 0; c4 < 8; ++c4) {
            float4 vv = vp[c4];
            o[c4 * 4 + 0] += p * vv.x; o[c4 * 4 + 1] += p * vv.y;
            o[c4 * 4 + 2] += p * vv.z; o[c4 * 4 + 3] += p * vv.w;
        }
    }
    float inv = 1.f / den;
    float* op = o3 + ((size_t)b * NQ_ + N) * 32;
    #pragma unroll
    for (int c = 0; c < 32; ++c) op[c] = o[c] * inv;
}

// ============================================================
// K10: tiled GEMM  out += r1 * (o3 @ W_out3^T + bias)
// ============================================================
__global__ __launch_bounds__(256) void k_final(const float* __restrict__ o3,
        const float* __restrict__ W, const float* __restrict__ bias,
        const float* __restrict__ r1p, float* __restrict__ out) {
    __shared__ float o3T[32 * 128];     // [k][row]
    __shared__ float WT[32 * 260];      // [k][c]
    int t = threadIdx.x;
    int R0 = blockIdx.x * 128;
    {
        int row = t >> 1, k0 = (t & 1) * 16;
        int R = R0 + row;
        int b = R & 3, N = R >> 2;
        const float* src = o3 + ((size_t)b * NQ_ + N) * 32 + k0;
        #pragma unroll
        for (int j = 0; j < 16; ++j) o3T[(k0 + j) * 128 + row] = src[j];
    }
    for (int d = t; d < 8192; d += 256) {
        int c = d >> 5, k = d & 31;
        WT[k * 260 + c] = W[d];
    }
    __syncthreads();
    int tc = t & 15;
    int tr = t >> 4;
    int r0 = tr * 8;
    float acc[8][16];
    #pragma unroll
    for (int i = 0; i < 8; ++i)
        #pragma unroll
        for (int j = 0; j < 16; ++j) acc[i][j] = 0.f;
    #pragma unroll 1
    for (int k = 0; k < 32; ++k) {
        float a[8];
        *(float4*)&a[0] = *(const float4*)&o3T[k * 128 + r0];
        *(float4*)&a[4] = *(const float4*)&o3T[k * 128 + r0 + 4];
        float wv[16];
        #pragma unroll
        for (int ci = 0; ci < 16; ++ci) wv[ci] = WT[k * 260 + tc + 16 * ci];
        #pragma unroll
        for (int i = 0; i < 8; ++i)
            #pragma unroll
            for (int j = 0; j < 16; ++j) acc[i][j] += a[i] * wv[j];
    }
    float r1 = r1p[0];
    float bs[16];
    #pragma unroll
    for (int ci = 0; ci < 16; ++ci) bs[ci] = bias[tc + 16 * ci];
    #pragma unroll 1
    for (int i = 0; i < 8; ++i) {
        size_t rowbase = (size_t)(R0 + r0 + i) * 256;
        #pragma unroll
        for (int j = 0; j < 16; ++j) {
            size_t oi = rowbase + tc + 16 * j;
            out[oi] = r1 * (acc[i][j] + bs[j]) + out[oi];
        }
    }
}

// ============================================================
extern "C" void kernel_launch(void* const* d_in, const int* in_sizes, int n_in,
                              void* d_out, int out_size, void* d_ws, size_t ws_size,
                              hipStream_t stream) {
    (void)in_sizes; (void)n_in; (void)out_size; (void)ws_size;
    const float* x      = (const float*)d_in[0];
    const float* W_qkv  = (const float*)d_in[1];
    const float* b_qkv  = (const float*)d_in[2];
    const float* W_fc   = (const float*)d_in[3];
    const float* b_fc   = (const float*)d_in[4];
    const float* W_doff = (const float*)d_in[5];
    const float* b_doff = (const float*)d_in[6];
    const float* W_dep  = (const float*)d_in[7];
    const float* b_dep  = (const float*)d_in[8];
    const float* W_st   = (const float*)d_in[9];
    const float* b_st   = (const float*)d_in[10];
    const float* W_off2d= (const float*)d_in[11];
    const float* b_off2d= (const float*)d_in[12];
    const float* W_attw = (const float*)d_in[13];
    const float* b_attw = (const float*)d_in[14];
    const float* W_val  = (const float*)d_in[15];
    const float* b_val  = (const float*)d_in[16];
    const float* W_out2d= (const float*)d_in[17];
    const float* b_out2d= (const float*)d_in[18];
    const float* W_q3   = (const float*)d_in[19];
    const float* b_q3   = (const float*)d_in[20];
    const float* W_k3   = (const float*)d_in[21];
    const float* b_k3   = (const float*)d_in[22];
    const float* W_v3   = (const float*)d_in[23];
    const float* b_v3   = (const float*)d_in[24];
    const float* W_offA = (const float*)d_in[25];
    const float* b_offA = (const float*)d_in[26];
    const float* W_offB = (const float*)d_in[27];
    const float* b_offB = (const float*)d_in[28];
    const float* W_out3 = (const float*)d_in[29];
    const float* b_out3 = (const float*)d_in[30];
    const float* rate1  = (const float*)d_in[31];
    const float* rate2  = (const float*)d_in[32];

    float* ws  = (float*)d_ws;
    float* out = (float*)d_out;
    float* qhp = ws + WS_QH;
    float* khp = ws + WS_KH;
    float* fn2 = ws + WS_FIN2;
    float* off = ws + WS_OFF;
    float* v2  = ws + WS_V2;
    float* a2  = ws + WS_A2;
    float* q3  = ws + WS_Q3;
    float* kf  = ws + WS_KF;
    float* vf  = ws + WS_VF;
    float* crd = ws + WS_CRD;
    float* ks  = ws + WS_KS;
    float* vs  = ws + WS_VS;
    float* o3w = ws + WS_O3;

    k_qkv      <<<3200,   256, 0, stream>>>(x, W_qkv, b_qkv, qhp, khp);
    k_fin_v2   <<<400,    256, 0, stream>>>(qhp, khp, W_fc, b_fc, W_val, b_val, fn2, v2);
    k_offconv  <<<400,    256, 0, stream>>>(fn2, W_doff, b_doff, off);
    k_depst    <<<1600,   256, 0, stream>>>(fn2, off, W_dep, b_dep, W_st, b_st, rate2, out);
    k_attn2d   <<<400,    256, 0, stream>>>(qhp, v2, W_off2d, b_off2d, W_attw, b_attw, W_out2d, b_out2d, a2);
    k_qkv3     <<<400,    256, 0, stream>>>(a2, W_q3, b_q3, W_k3, b_k3, W_v3, b_v3, q3, kf, vf);
    k_offs3d   <<<200,    256, 0, stream>>>(q3, W_offA, b_offA, W_offB, b_offB, crd);
    k_trisample<<<200,    256, 0, stream>>>(kf, vf, crd, ks, vs);
    k_attn3d   <<<400,    256, 0, stream>>>(q3, ks, vs, o3w);
    k_final    <<<800,    256, 0, stream>>>(o3w, W_out3, b_out3, rate1, out);
}